// Round 7
// baseline (4901.120 us; speedup 1.0000x reference)
//
#include <hip/hip_runtime.h>
#include <math.h>

constexpr int kB  = 256;
constexpr int kT  = 512;
constexpr int kNS = 64;
constexpr int kH  = 128;

__device__ __forceinline__ float sigmoidf_(float v) { return 1.0f / (1.0f + __expf(-v)); }
__device__ __forceinline__ float dot4(float4 a, float4 b) {
    return a.x*b.x + a.y*b.y + a.z*b.z + a.w*b.w;
}

// One-time prep in d_ws: WhhT[384][128] (transpose) and AT[m][n][d] (per-m transpose).
extern "C" __global__ void __launch_bounds__(256)
prep_ws(const float* __restrict__ Whh, const float* __restrict__ A,
        float* __restrict__ WhhT, float* __restrict__ AT) {
    const int o = blockIdx.x * 256 + threadIdx.x;       // 0..98303
    if (o < 49152) {
        const int j = o >> 7, k = o & 127;
        WhhT[o] = Whh[k * 384 + j];
    } else {
        const int p = o - 49152;
        const int m = p >> 14, n = (p >> 8) & 63, d = p & 255;
        AT[p] = A[(m * 256 + d) * 64 + n];
    }
}

// One block (768 threads = 12 waves, 3/SIMD) per batch row. 4 barriers/step.
//  PA: waves0-5 K (2 rows/thr, S regs) | waves6-11 gh rows 0-191   -> barrier
//  PB: waves6-11 einsum (2 cols/thr, A regs) | waves0-5 gh 192-383 -> barrier
//  PE: waves0-1 GRU + logit partials | wave2 prefetch              -> barrier
//  PF: wave0 softmax/gate/mix tail                                 -> barrier
extern "C" __global__ void __launch_bounds__(768, 3)
disc_kernel(const float* __restrict__ x,   const float* __restrict__ y,
            const float* __restrict__ U,   const float* __restrict__ S,
            const float* __restrict__ Wih, const float* __restrict__ bih,
            const float* __restrict__ bhh, const float* __restrict__ Wd,
            const float* __restrict__ bd,  const float* __restrict__ WhhT,
            const float* __restrict__ AT,
            float* __restrict__ out_o,  float* __restrict__ out_p)
{
    const int b    = blockIdx.x;
    const int tid  = threadIdx.x;
    const int lane = tid & 63;
    const int wid  = tid >> 6;

    __shared__ __align__(16) float sh_K[768];
    __shared__ __align__(16) float sh_part[800];     // stride 196 per c (pad 4)
    __shared__ __align__(16) float sh_gh[384];
    __shared__ __align__(16) float sh_h[2][kH];      // parity double buffer
    __shared__ __align__(16) float sh_s[kNS];
    __shared__ __align__(16) float sh_Wih[4 * 384];
    __shared__ __align__(16) float sh_bih[384];
    __shared__ __align__(16) float sh_bhh[384];
    __shared__ float sh_Wd[384];                     // row 127 zero-padded
    __shared__ float sh_bd[4];
    __shared__ float sh_enc[8];                      // per-wave K maxes (waves 0-5)
    __shared__ float sh_lp[8];                       // logit partials [wave*4+m]
    __shared__ __align__(16) float sh_xt[4];
    __shared__ float sh_x2, sh_s2, sh_err;
    __shared__ float sh_yt[2];

    // ---- Uniform persistent cache: 32 float4 + U/C ----------------------
    float4 cache4[32];
    float4 Uc[2];
    float  Cc[2];
    if (tid < 384) {
        // K role: S rows 2t, 2t+1
        const float4* S4 = reinterpret_cast<const float4*>(S);
        const int r0 = 2 * tid;
#pragma unroll
        for (int half = 0; half < 2; ++half) {
            float ss = 0.f;
#pragma unroll
            for (int j = 0; j < 16; ++j) {
                cache4[half * 16 + j] = S4[(r0 + half) * 16 + j];
                ss += dot4(cache4[half * 16 + j], cache4[half * 16 + j]);
            }
            Uc[half] = reinterpret_cast<const float4*>(U)[r0 + half];
            Cc[half] = -0.5f * (dot4(Uc[half], Uc[half]) + ss);
        }
    } else {
        // einsum role: AT slices for chunk q = 2*(wid-6)+(lane>>5), cols n, n+32
        const int q = 2 * (wid - 6) + (lane >> 5);
        const int m = q >> 2, c = q & 3, n = lane & 31;
        const float4* AT4 = reinterpret_cast<const float4*>(AT);
#pragma unroll
        for (int j = 0; j < 16; ++j) {
            cache4[j]      = AT4[(m * 64 + n)      * 64 + c * 16 + j];
            cache4[16 + j] = AT4[(m * 64 + n + 32) * 64 + c * 16 + j];
        }
        Uc[0] = Uc[1] = make_float4(0.f, 0.f, 0.f, 0.f);
        Cc[0] = Cc[1] = 0.f;
    }

    // PF-wave persistent gate state (all lanes of wave 0 keep identical copies)
    float g0 = 0.3333f, g1 = 0.3333f, g2 = 0.3334f;

    // ---- LDS preload -----------------------------------------------------
    for (int i = tid; i < 1536; i += 768) sh_Wih[i] = Wih[i];
    for (int i = tid; i < 384; i += 768) {
        sh_bih[i] = bih[i];
        sh_bhh[i] = bhh[i];
        sh_Wd[i]  = (i < 381) ? Wd[i] : 0.f;
    }
    if (tid < 3) sh_bd[tid] = bd[tid];
    if (tid < kNS) sh_s[tid] = 0.f;
    if (tid < kH)  sh_h[0][tid] = 0.f;
    if (tid == 0) {
        sh_err = 1.0f; sh_s2 = 0.f;
        float4 xv = reinterpret_cast<const float4*>(x)[(size_t)b * kT];
        reinterpret_cast<float4*>(sh_xt)[0] = xv;
        sh_x2 = dot4(xv, xv);
        sh_yt[0] = y[(size_t)b * kT];
    }
    __syncthreads();

    for (int t = 0; t < kT; ++t) {
        const int par  = t & 1;
        const int par1 = (t + 1) & 1;

        // ===== PA: K (waves 0-5) | gh rows 0-191 (waves 6-11, h_t) =========
        if (tid < 384) {
            const float scal = -0.5f * (sh_x2 + sh_s2);
            const float4 xt4 = reinterpret_cast<const float4*>(sh_xt)[0];
            const float4* s4 = reinterpret_cast<const float4*>(sh_s);
            float d0 = 0.f, d1 = 0.f;
#pragma unroll
            for (int j = 0; j < 16; ++j) {
                const float4 sv = s4[j];               // broadcast, amortized x2
                d0 += dot4(sv, cache4[j]);
                d1 += dot4(sv, cache4[16 + j]);
            }
            const float kk0 = __expf(scal + Cc[0] + dot4(xt4, Uc[0]) + d0);
            const float kk1 = __expf(scal + Cc[1] + dot4(xt4, Uc[1]) + d1);
            reinterpret_cast<float2*>(sh_K)[tid] = make_float2(kk0, kk1);
            float mx = fmaxf(kk0, kk1);
#pragma unroll
            for (int o = 32; o > 0; o >>= 1) mx = fmaxf(mx, __shfl_xor(mx, o, 64));
            if (lane == 0) sh_enc[wid] = mx;           // wave w covers m = w>>1
        } else {
            const int u = tid - 384;
            const int row = u >> 1, half = u & 1;
            const float4* W4 = reinterpret_cast<const float4*>(WhhT) + row * 32 + half * 16;
            const float4* h4 = reinterpret_cast<const float4*>(sh_h[par]) + half * 16;
            float acc = half ? 0.f : sh_bhh[row];
#pragma unroll 4
            for (int k = 0; k < 16; ++k) acc += dot4(h4[k], W4[k]);
            acc += __shfl_xor(acc, 1, 64);
            if (half == 0) sh_gh[row] = acc;
        }
        __syncthreads();                                  // (1)

        // ===== PB: einsum (waves 6-11) | gh rows 192-383 (waves 0-5, h_t) ==
        if (tid >= 384) {
            const int q = 2 * (wid - 6) + (lane >> 5);
            const int m = q >> 2, c = q & 3, n = lane & 31;
            const float4* K4 = reinterpret_cast<const float4*>(sh_K + m * 256 + c * 64);
            float a0 = 0.f, a1 = 0.f;
#pragma unroll
            for (int j = 0; j < 16; ++j) {
                const float4 kv = K4[j];               // 2-way broadcast (free)
                a0 += kv.x*cache4[j].x      + kv.y*cache4[j].y
                    + kv.z*cache4[j].z      + kv.w*cache4[j].w;
                a1 += kv.x*cache4[16+j].x   + kv.y*cache4[16+j].y
                    + kv.z*cache4[16+j].z   + kv.w*cache4[16+j].w;
            }
            sh_part[c * 196 + m * 64 + n]      = a0;
            sh_part[c * 196 + m * 64 + n + 32] = a1;
        } else {
            const int row = 192 + (tid >> 1), half = tid & 1;
            const float4* W4 = reinterpret_cast<const float4*>(WhhT) + row * 32 + half * 16;
            const float4* h4 = reinterpret_cast<const float4*>(sh_h[par]) + half * 16;
            float acc = half ? 0.f : sh_bhh[row];
#pragma unroll 4
            for (int k = 0; k < 16; ++k) acc += dot4(h4[k], W4[k]);
            acc += __shfl_xor(acc, 1, 64);
            if (half == 0) sh_gh[row] = acc;
        }
        __syncthreads();                                  // (2)

        // ===== PE: GRU + logit partials (waves 0-1) | prefetch (wave 2) ====
        if (tid < 128) {
            const float e0 = fmaxf(sh_enc[0], sh_enc[1]);
            const float e1 = fmaxf(sh_enc[2], sh_enc[3]);
            const float e2 = fmaxf(sh_enc[4], sh_enc[5]);
            const float er = sh_err;
            const int j = tid;
            const float gir = sh_bih[j]       + e0*sh_Wih[j]        + e1*sh_Wih[384 + j]
                                              + e2*sh_Wih[768 + j]  + er*sh_Wih[1152 + j];
            const float giz = sh_bih[128 + j] + e0*sh_Wih[128 + j]  + e1*sh_Wih[512 + j]
                                              + e2*sh_Wih[896 + j]  + er*sh_Wih[1280 + j];
            const float gin = sh_bih[256 + j] + e0*sh_Wih[256 + j]  + e1*sh_Wih[640 + j]
                                              + e2*sh_Wih[1024 + j] + er*sh_Wih[1408 + j];
            const float r  = sigmoidf_(gir + sh_gh[j]);
            const float z  = sigmoidf_(giz + sh_gh[128 + j]);
            const float nn = tanhf(gin + r * sh_gh[256 + j]);
            const float hn = (1.f - z) * nn + z * sh_h[par][j];
            sh_h[par1][j] = hn;
            // logit partials (Wd row 127 is zero-padded)
            float l0 = hn * sh_Wd[j*3+0];
            float l1 = hn * sh_Wd[j*3+1];
            float l2 = hn * sh_Wd[j*3+2];
#pragma unroll
            for (int o = 32; o > 0; o >>= 1) {
                l0 += __shfl_xor(l0, o, 64);
                l1 += __shfl_xor(l1, o, 64);
                l2 += __shfl_xor(l2, o, 64);
            }
            if (lane == 0) {
                sh_lp[wid * 4 + 0] = l0;
                sh_lp[wid * 4 + 1] = l1;
                sh_lp[wid * 4 + 2] = l2;
            }
        } else if (tid == 128) {
            if ((t + 1) < kT) {
                float4 xv = reinterpret_cast<const float4*>(x)[(size_t)b * kT + t + 1];
                reinterpret_cast<float4*>(sh_xt)[0] = xv;
                sh_x2 = dot4(xv, xv);
                sh_yt[par1] = y[(size_t)b * kT + t + 1];
            }
        }
        __syncthreads();                                  // (3)

        // ===== PF: wave 0 — softmax / gate blend / mix / err ===============
        if (tid < 64) {
            const float l0 = sh_lp[0] + sh_lp[4] + sh_bd[0];
            const float l1 = sh_lp[1] + sh_lp[5] + sh_bd[1];
            const float l2 = sh_lp[2] + sh_lp[6] + sh_bd[2];
            const float mx = fmaxf(l0, fmaxf(l1, l2));
            const float x0 = __expf(l0 - mx), x1 = __expf(l1 - mx), x2 = __expf(l2 - mx);
            const float theta = sigmoidf_(sh_h[par1][127]);
            const float inv = theta / (x0 + x1 + x2);
            const float omt = 1.f - theta;
            g0 = x0*inv + g0*omt;
            g1 = x1*inv + g1*omt;
            g2 = x2*inv + g2*omt;
            const float ns0 = (sh_part[lane]            + sh_part[196 + lane])
                            + (sh_part[392 + lane]      + sh_part[588 + lane]);
            const float ns1 = (sh_part[64 + lane]       + sh_part[260 + lane])
                            + (sh_part[456 + lane]      + sh_part[652 + lane]);
            const float ns2 = (sh_part[128 + lane]      + sh_part[324 + lane])
                            + (sh_part[520 + lane]      + sh_part[716 + lane]);
            const float sn = g0*ns0 + g1*ns1 + g2*ns2;
            sh_s[lane] = sn;
            if (lane == 0)
                out_p[(size_t)b * kT + t] = g0*(1.f-g0) + g1*(1.f-g1) + g2*(1.f-g2);
            if (lane == 63) {
                out_o[(size_t)b * kT + t] = sn;
                sh_err = sn - sh_yt[par];
            }
            float ss = sn * sn;
#pragma unroll
            for (int o = 32; o > 0; o >>= 1) ss += __shfl_xor(ss, o, 64);
            if (lane == 0) sh_s2 = ss;
        }
        __syncthreads();                                  // (4)
    }
}

extern "C" void kernel_launch(void* const* d_in, const int* in_sizes, int n_in,
                              void* d_out, int out_size, void* d_ws, size_t ws_size,
                              hipStream_t stream)
{
    const float* x   = (const float*)d_in[0];
    const float* y   = (const float*)d_in[1];
    const float* U   = (const float*)d_in[2];
    const float* S   = (const float*)d_in[3];
    const float* A   = (const float*)d_in[4];
    const float* Wih = (const float*)d_in[5];
    const float* Whh = (const float*)d_in[6];
    const float* bih = (const float*)d_in[7];
    const float* bhh = (const float*)d_in[8];
    const float* Wd  = (const float*)d_in[9];
    const float* bd  = (const float*)d_in[10];

    float* WhhT  = (float*)d_ws;                 // 49152 floats
    float* AT    = WhhT + 49152;                 // 49152 floats (total 384 KB)
    float* out_o = (float*)d_out;                // (B, T) preds
    float* out_p = out_o + kB * kT;              // (B, T, 1) penalties

    hipLaunchKernelGGL(prep_ws, dim3(384), dim3(256), 0, stream, Whh, A, WhhT, AT);
    hipLaunchKernelGGL(disc_kernel, dim3(kB), dim3(768), 0, stream,
                       x, y, U, S, Wih, bih, bhh, Wd, bd, WhhT, AT, out_o, out_p);
}

// Round 8
// 4650.603 us; speedup vs baseline: 1.0539x; 1.0539x over previous
//
#include <hip/hip_runtime.h>
#include <math.h>

constexpr int kB  = 256;
constexpr int kT  = 512;
constexpr int kNS = 64;
constexpr int kH  = 128;

__device__ __forceinline__ float sigmoidf_(float v) { return 1.0f / (1.0f + __expf(-v)); }
__device__ __forceinline__ float dot4(float4 a, float4 b) {
    return a.x*b.x + a.y*b.y + a.z*b.z + a.w*b.w;
}

// One-time: transpose Whh[128][384] -> WhhT[384][128] in d_ws.
extern "C" __global__ void __launch_bounds__(256)
whh_transpose(const float* __restrict__ Whh, float* __restrict__ WhhT) {
    const int o = blockIdx.x * 256 + threadIdx.x;   // 0..49151
    const int j = o >> 7, k = o & 127;
    WhhT[o] = Whh[k * 384 + j];
}

// One block (512 threads) per batch row. 3 barriers/step:
//  P1: gh stream (lanes<48/wave, h_t) + K (regs) + wave-sync LDS exchange
//      + wave-private einsum (reads ONLY own-wave K: no barrier needed)
//  P2: GRU+logit partials (thr 0-127) | ns pre-reduce (thr 128-319) | prefetch
//  P3: wave0 softmax/gate/mix/err tail
extern "C" __global__ void __launch_bounds__(512, 2)
disc_kernel(const float* __restrict__ x,   const float* __restrict__ y,
            const float* __restrict__ U,   const float* __restrict__ S,
            const float* __restrict__ A,   const float* __restrict__ Wih,
            const float* __restrict__ bih, const float* __restrict__ bhh,
            const float* __restrict__ Wd,  const float* __restrict__ bd,
            const float* __restrict__ WhhT,
            float* __restrict__ out_o,  float* __restrict__ out_p)
{
    const int b    = blockIdx.x;
    const int tid  = threadIdx.x;
    const int lane = tid & 63;
    const int wid  = tid >> 6;
    const int hb   = tid & 1;

    __shared__ __align__(16) float sh_K[768];
    __shared__ __align__(16) float sh_part[512];
    __shared__ __align__(16) float sh_part2[512];
    __shared__ __align__(16) float sh_ns[192];
    __shared__ __align__(16) float sh_gh[384];
    __shared__ __align__(16) float sh_h[2][kH];      // parity double buffer
    __shared__ __align__(16) float sh_s[kNS];
    __shared__ __align__(16) float sh_Wih[4 * 384];
    __shared__ __align__(16) float sh_bih[384];
    __shared__ __align__(16) float sh_bhh[384];
    __shared__ float sh_Wd[384];                     // row 127 zero-padded
    __shared__ float sh_bd[4];
    __shared__ float sh_encA[8];
    __shared__ float sh_encB[8];
    __shared__ float sh_lp[8];                       // logit partials [wave*4+m]
    __shared__ __align__(16) float sh_xt[4];
    __shared__ float sh_x2, sh_s2, sh_err;
    __shared__ float sh_yt[2];

    // ---- Persistent register caches (identical layout to R6) -------------
    const float4* S4 = reinterpret_cast<const float4*>(S);
    const float4* U4 = reinterpret_cast<const float4*>(U);

    float4 Sa[16]; float4 Ua; float Ca;       // full K-row = tid
    float4 Sb[8];  float Ub0, Ub1; float Cb;  // half of K-row 512+(tid>>1)
    {
        float ss = 0.f;
#pragma unroll
        for (int j = 0; j < 16; ++j) { Sa[j] = S4[tid * 16 + j]; ss += dot4(Sa[j], Sa[j]); }
        Ua = U4[tid];
        Ca = -0.5f * (dot4(Ua, Ua) + ss);
    }
    const int pbrow = 512 + (tid >> 1);
    {
        float ss = 0.f;
#pragma unroll
        for (int j = 0; j < 8; ++j) { Sb[j] = S4[pbrow * 16 + hb * 8 + j]; ss += dot4(Sb[j], Sb[j]); }
        Ub0 = U[pbrow * 4 + hb * 2 + 0];
        Ub1 = U[pbrow * 4 + hb * 2 + 1];
        Cb = -0.5f * (Ub0*Ub0 + Ub1*Ub1 + ss);
    }
    float A1[64];                              // d in [64*wid, 64*wid+64), n=lane
#pragma unroll
    for (int dd = 0; dd < 64; ++dd)
        A1[dd] = A[((wid >> 2) * 256 + (wid & 3) * 64 + dd) * 64 + lane];
    float A2[32];                              // d in [512+32*wid, +32), n=lane
#pragma unroll
    for (int dd = 0; dd < 32; ++dd)
        A2[dd] = A[(512 + (wid >> 1) * 64 + (wid & 1) * 32 + dd) * 64 + lane];

    // gh row owned by this thread (lanes 0-47 of each wave): 384 rows total
    const int ghrow = wid * 48 + lane;         // valid iff lane < 48

    // P3-wave persistent gate state
    float g0 = 0.3333f, g1 = 0.3333f, g2 = 0.3334f;

    // ---- LDS preload -----------------------------------------------------
    for (int i = tid; i < 1536; i += 512) sh_Wih[i] = Wih[i];
    for (int i = tid; i < 384; i += 512) {
        sh_bih[i] = bih[i];
        sh_bhh[i] = bhh[i];
        sh_Wd[i]  = (i < 381) ? Wd[i] : 0.f;
    }
    if (tid < 3) sh_bd[tid] = bd[tid];
    if (tid < kNS) sh_s[tid] = 0.f;
    if (tid < kH)  sh_h[0][tid] = 0.f;
    if (tid == 0) {
        sh_err = 1.0f; sh_s2 = 0.f;
        float4 xv = reinterpret_cast<const float4*>(x)[(size_t)b * kT];
        reinterpret_cast<float4*>(sh_xt)[0] = xv;
        sh_x2 = dot4(xv, xv);
        sh_yt[0] = y[(size_t)b * kT];
    }
    __syncthreads();

    for (int t = 0; t < kT; ++t) {
        const int par  = t & 1;
        const int par1 = (t + 1) & 1;

        // =================== P1 (fused, one barrier) =======================
        // (a) gh stream: row ghrow, gh = bhh[row] + WhhT[row,:] . h_t
        float ghacc = 0.f;
        if (lane < 48) {
            const float4* W4 = reinterpret_cast<const float4*>(WhhT) + ghrow * 32;
            const float4* h4 = reinterpret_cast<const float4*>(sh_h[par]);
            ghacc = sh_bhh[ghrow];
#pragma unroll 4
            for (int k4 = 0; k4 < 32; ++k4) ghacc += dot4(h4[k4], W4[k4]);
        }
        // (b) K compute (registers + LDS broadcasts)
        {
            const float scal = -0.5f * (sh_x2 + sh_s2);
            const float4 xt4 = reinterpret_cast<const float4*>(sh_xt)[0];
            const float4* s4 = reinterpret_cast<const float4*>(sh_s);
            float d0 = 0.f, d1 = 0.f, db = 0.f;
#pragma unroll
            for (int j = 0; j < 8; ++j) {
                d0 += dot4(s4[2*j],     Sa[2*j]);
                d1 += dot4(s4[2*j + 1], Sa[2*j + 1]);
            }
#pragma unroll
            for (int j = 0; j < 8; ++j)  db += dot4(s4[hb * 8 + j], Sb[j]);
            const float kk_a = __expf(scal + Ca + dot4(xt4, Ua) + d0 + d1);
            const float xbp  = hb ? (xt4.z*Ub0 + xt4.w*Ub1) : (xt4.x*Ub0 + xt4.y*Ub1);
            const float ph   = db + Cb + xbp;
            const float po   = __shfl_xor(ph, 1, 64);
            const float kk_b = __expf(scal + ph + po);
            sh_K[tid] = kk_a;
            if (hb == 0) sh_K[512 + (tid >> 1)] = kk_b;
            float mA = kk_a, mB = kk_b;
#pragma unroll
            for (int o = 32; o > 0; o >>= 1) {
                mA = fmaxf(mA, __shfl_xor(mA, o, 64));
                mB = fmaxf(mB, __shfl_xor(mB, o, 64));
            }
            if (lane == 0) { sh_encA[wid] = mA; sh_encB[wid] = mB; }
        }
        if (lane < 48) sh_gh[ghrow] = ghacc;
        // Wave-synchronous LDS exchange: einsum below reads ONLY this wave's
        // K values; DS ops within a wave complete in order — just drain lgkm.
        asm volatile("s_waitcnt lgkmcnt(0)" ::: "memory");
        // (c) einsum, wave-private K (broadcast reads)
        {
            const float4* K4 = reinterpret_cast<const float4*>(sh_K + wid * 64);
            float acc = 0.f;
#pragma unroll
            for (int j = 0; j < 16; ++j) {
                const float4 kv = K4[j];
                acc += kv.x*A1[4*j] + kv.y*A1[4*j+1] + kv.z*A1[4*j+2] + kv.w*A1[4*j+3];
            }
            sh_part[tid] = acc;
            const float4* K4b = reinterpret_cast<const float4*>(
                                    sh_K + 512 + (wid >> 1) * 64 + (wid & 1) * 32);
            float accb = 0.f;
#pragma unroll
            for (int j = 0; j < 8; ++j) {
                const float4 kv = K4b[j];
                accb += kv.x*A2[4*j] + kv.y*A2[4*j+1] + kv.z*A2[4*j+2] + kv.w*A2[4*j+3];
            }
            sh_part2[tid] = accb;
        }
        __syncthreads();                                  // (1)

        // =================== P2 ============================================
        if (tid < 128) {
            const float e0 = fmaxf(fmaxf(sh_encA[0], sh_encA[1]), fmaxf(sh_encA[2], sh_encA[3]));
            const float e1 = fmaxf(fmaxf(sh_encA[4], sh_encA[5]), fmaxf(sh_encA[6], sh_encA[7]));
            const float e2 = fmaxf(fmaxf(fmaxf(sh_encB[0], sh_encB[1]), fmaxf(sh_encB[2], sh_encB[3])),
                                   fmaxf(fmaxf(sh_encB[4], sh_encB[5]), fmaxf(sh_encB[6], sh_encB[7])));
            const float er = sh_err;
            const int j = tid;
            const float gir = sh_bih[j]       + e0*sh_Wih[j]        + e1*sh_Wih[384 + j]
                                              + e2*sh_Wih[768 + j]  + er*sh_Wih[1152 + j];
            const float giz = sh_bih[128 + j] + e0*sh_Wih[128 + j]  + e1*sh_Wih[512 + j]
                                              + e2*sh_Wih[896 + j]  + er*sh_Wih[1280 + j];
            const float gin = sh_bih[256 + j] + e0*sh_Wih[256 + j]  + e1*sh_Wih[640 + j]
                                              + e2*sh_Wih[1024 + j] + er*sh_Wih[1408 + j];
            const float r  = sigmoidf_(gir + sh_gh[j]);
            const float z  = sigmoidf_(giz + sh_gh[128 + j]);
            const float nn = tanhf(gin + r * sh_gh[256 + j]);
            const float hn = (1.f - z) * nn + z * sh_h[par][j];
            sh_h[par1][j] = hn;
            float l0 = hn * sh_Wd[j*3+0];
            float l1 = hn * sh_Wd[j*3+1];
            float l2 = hn * sh_Wd[j*3+2];
#pragma unroll
            for (int o = 32; o > 0; o >>= 1) {
                l0 += __shfl_xor(l0, o, 64);
                l1 += __shfl_xor(l1, o, 64);
                l2 += __shfl_xor(l2, o, 64);
            }
            if (lane == 0) {
                sh_lp[wid * 4 + 0] = l0;
                sh_lp[wid * 4 + 1] = l1;
                sh_lp[wid * 4 + 2] = l2;
            }
        } else if (tid < 320) {
            const int idx = tid - 128;                     // 0..191
            const int m = idx >> 6, n = idx & 63;
            float v;
            if (m == 0)
                v = (sh_part[n]        + sh_part[64 + n])
                  + (sh_part[128 + n]  + sh_part[192 + n]);
            else if (m == 1)
                v = (sh_part[256 + n]  + sh_part[320 + n])
                  + (sh_part[384 + n]  + sh_part[448 + n]);
            else
                v = ((sh_part2[n]        + sh_part2[64 + n])
                  +  (sh_part2[128 + n]  + sh_part2[192 + n]))
                  + ((sh_part2[256 + n]  + sh_part2[320 + n])
                  +  (sh_part2[384 + n]  + sh_part2[448 + n]));
            sh_ns[idx] = v;
        } else if (tid == 320) {
            if ((t + 1) < kT) {
                float4 xv = reinterpret_cast<const float4*>(x)[(size_t)b * kT + t + 1];
                reinterpret_cast<float4*>(sh_xt)[0] = xv;
                sh_x2 = dot4(xv, xv);
                sh_yt[par1] = y[(size_t)b * kT + t + 1];
            }
        }
        __syncthreads();                                  // (2)

        // =================== P3: wave 0 tail ===============================
        if (tid < 64) {
            const float l0 = sh_lp[0] + sh_lp[4] + sh_bd[0];
            const float l1 = sh_lp[1] + sh_lp[5] + sh_bd[1];
            const float l2 = sh_lp[2] + sh_lp[6] + sh_bd[2];
            const float mx = fmaxf(l0, fmaxf(l1, l2));
            const float x0 = __expf(l0 - mx), x1 = __expf(l1 - mx), x2 = __expf(l2 - mx);
            const float theta = sigmoidf_(sh_h[par1][127]);
            const float inv = theta / (x0 + x1 + x2);
            const float omt = 1.f - theta;
            g0 = x0*inv + g0*omt;
            g1 = x1*inv + g1*omt;
            g2 = x2*inv + g2*omt;
            const float sn = g0*sh_ns[lane] + g1*sh_ns[64 + lane] + g2*sh_ns[128 + lane];
            sh_s[lane] = sn;
            if (lane == 0)
                out_p[(size_t)b * kT + t] = g0*(1.f-g0) + g1*(1.f-g1) + g2*(1.f-g2);
            if (lane == 63) {
                out_o[(size_t)b * kT + t] = sn;
                sh_err = sn - sh_yt[par];
            }
            float ss = sn * sn;
#pragma unroll
            for (int o = 32; o > 0; o >>= 1) ss += __shfl_xor(ss, o, 64);
            if (lane == 0) sh_s2 = ss;
        }
        __syncthreads();                                  // (3)
    }
}

extern "C" void kernel_launch(void* const* d_in, const int* in_sizes, int n_in,
                              void* d_out, int out_size, void* d_ws, size_t ws_size,
                              hipStream_t stream)
{
    const float* x   = (const float*)d_in[0];
    const float* y   = (const float*)d_in[1];
    const float* U   = (const float*)d_in[2];
    const float* S   = (const float*)d_in[3];
    const float* A   = (const float*)d_in[4];
    const float* Wih = (const float*)d_in[5];
    const float* Whh = (const float*)d_in[6];
    const float* bih = (const float*)d_in[7];
    const float* bhh = (const float*)d_in[8];
    const float* Wd  = (const float*)d_in[9];
    const float* bd  = (const float*)d_in[10];

    float* WhhT  = (float*)d_ws;                 // 49152 floats = 192 KB scratch
    float* out_o = (float*)d_out;                // (B, T) preds
    float* out_p = out_o + kB * kT;              // (B, T, 1) penalties

    hipLaunchKernelGGL(whh_transpose, dim3(192), dim3(256), 0, stream, Whh, WhhT);
    hipLaunchKernelGGL(disc_kernel, dim3(kB), dim3(512), 0, stream,
                       x, y, U, S, A, Wih, bih, bhh, Wd, bd, WhhT, out_o, out_p);
}